// Round 8
// baseline (11940.166 us; speedup 1.0000x reference)
//
#include <hip/hip_runtime.h>

typedef __attribute__((ext_vector_type(8))) short short8;
typedef __attribute__((ext_vector_type(16))) float f32x16;
typedef __attribute__((ext_vector_type(4))) float f32x4;
typedef __attribute__((ext_vector_type(2))) unsigned int u32x2;
typedef unsigned short u16;
typedef unsigned int u32;

// ---------------- workspace layout (bytes) ----------------
// xb:  [512][64 b][512 i] bf16                        = 33,554,432
// h0h: [513][128 chunk][64 b][8 u] bf16 (slot t+1=h[t]) = 67,239,936
// h1h: same                                            = 67,239,936
// f0:  [2 class][128 cu] tags, 32B stride              = 8,192
// f1:  same                                            = 8,192
#define XB_OFF 0ul
#define H0_OFF 33554432ul
#define H1_OFF 100794368ul
#define F0_OFF 168034304ul
#define F1_OFF 168042496ul
#define FLAGS_LEN 16384ul

#define LDS_TOTAL 131072   // 32 cols * K2 (K2 = 4096 B for layer 1)

__device__ __forceinline__ u16 f2bf(float f) {
  u32 u = __float_as_uint(f);
  return (u16)((u + 0x7fffu + ((u >> 16) & 1u)) >> 16);   // RNE
}
__device__ __forceinline__ float bf2f(u16 s) { return __uint_as_float(((u32)s) << 16); }

// x[b][t][i] fp32 -> xb[t][b][i] bf16
__global__ __launch_bounds__(256) void prep_x(const float* __restrict__ x,
                                              u16* __restrict__ xb) {
  u32 stride = gridDim.x * blockDim.x;
  for (u32 e = blockIdx.x * blockDim.x + threadIdx.x; e < 16777216u; e += stride) {
    u32 i = e & 511u, b = (e >> 9) & 63u, t = e >> 15;
    xb[e] = f2bf(x[((size_t)b << 18) + ((size_t)t << 9) + i]);
  }
}

// Persistent kernel: 256 blocks x 192 threads (2 compute waves + 1 clock-keeper).
// Blocks 0..127: layer0 (K=1536=[x|h0prev]); 128..255: layer1 (K=2048=[h0cur|h1prev]).
// mfma 32x32x16, M=gate-cols(32/CU), N=batches(32/wave-class): LSTM cell update is
// fully lane-local (i,f,g,o of unit u in regs r,4+r,8+r,12+r) -> no barriers, no
// LDS reduce; each wave runs poll->load->mfma->nonlin->store->tag autonomously.
__global__ __launch_bounds__(192, 1) void lstm_persist(
    const u16* __restrict__ xb,
    const float* __restrict__ wih0, const float* __restrict__ whh0,
    const float* __restrict__ bih0, const float* __restrict__ bhh0,
    const float* __restrict__ wih1, const float* __restrict__ whh1,
    const float* __restrict__ bih1, const float* __restrict__ bhh1,
    u16* __restrict__ h0h, u16* __restrict__ h1h,
    u32* __restrict__ f0, u32* __restrict__ f1,
    const float* __restrict__ fc_w, const float* __restrict__ fc_b,
    float* __restrict__ out) {
  extern __shared__ char smem[];
  const int cu = blockIdx.x;
  const int layer = cu >> 7;
  const int lcu = cu & 127;
  const int U0 = lcu * 8;
  const int K2 = layer ? 4096 : 3072;      // bytes per LDS weight column
  const int tid = threadIdx.x;

  // ---- startup: pack 32 weight cols (bf16, col-major k, byte ^ (c&15)<<4) ----
  for (int n = 0; n < 32; ++n) {
    const int grow = (n >> 3) * 1024 + U0 + (n & 7);
    char* colbase = smem + n * K2;
    const u32 swn = (u32)(n & 15) << 4;
    if (!layer) {
      const float* rih = wih0 + (size_t)grow * 512;
      const float* rhh = whh0 + (size_t)grow * 1024;
      for (int k = tid; k < 1536; k += 192) {
        float v = (k < 512) ? rih[k] : rhh[k - 512];
        *(u16*)(colbase + (((u32)k * 2u) ^ swn)) = f2bf(v);
      }
    } else {
      const float* rih = wih1 + (size_t)grow * 1024;
      const float* rhh = whh1 + (size_t)grow * 1024;
      for (int k = tid; k < 2048; k += 192) {
        float v = (k < 1024) ? rih[k] : rhh[k - 1024];
        *(u16*)(colbase + (((u32)k * 2u) ^ swn)) = f2bf(v);
      }
    }
  }
  __syncthreads();   // last barrier in the kernel

  if (tid >= 128) {  // ---- clock-keeper wave: FMA spin until L1 done ----
    const u32* dp = f1;      // class0/cu0 tag reaches 512 at the end
    float a0 = 1.0f, a1 = 1.01f, a2 = 1.02f, a3 = 1.03f;
    const float m = 0.999999f;
    for (;;) {
      #pragma unroll 16
      for (int i = 0; i < 2048; ++i) {
        a0 = __builtin_fmaf(a0, m, 1e-9f); a1 = __builtin_fmaf(a1, m, 2e-9f);
        a2 = __builtin_fmaf(a2, m, 3e-9f); a3 = __builtin_fmaf(a3, m, 4e-9f);
      }
      u32 d;
      asm volatile("global_load_dword %0, %1, off sc0 sc1\n\ts_waitcnt vmcnt(0)"
                   : "=v"(d) : "v"(dp));
      if (d >= 512u) break;
    }
    asm volatile("" :: "v"(a0), "v"(a1), "v"(a2), "v"(a3));
    return;
  }

  const int wv = tid >> 6;          // batch class: b in [32*wv, 32*wv+32)
  const int lane = tid & 63;
  const int bq = lane & 31;
  const int hi = lane >> 5;         // k-half selector
  const int b = 32 * wv + bq;
  const int colA = lane & 31;       // A-operand row = gate-col
  const char* wcol = smem + (size_t)colA * K2;
  const u32 swz = (u32)(colA & 15) << 4;

  // bias regs: unit u = 4*hi + r
  float bi[4], bfr[4], bg[4], bo[4];
  {
    const float* s1 = layer ? bih1 : bih0;
    const float* s2 = layer ? bhh1 : bhh0;
    const int u0 = U0 + 4 * hi;
    f32x4 a, c;
    a = *(const f32x4*)(s1 + u0);        c = *(const f32x4*)(s2 + u0);
    #pragma unroll
    for (int r = 0; r < 4; ++r) bi[r] = a[r] + c[r];
    a = *(const f32x4*)(s1 + 1024 + u0); c = *(const f32x4*)(s2 + 1024 + u0);
    #pragma unroll
    for (int r = 0; r < 4; ++r) bfr[r] = a[r] + c[r];
    a = *(const f32x4*)(s1 + 2048 + u0); c = *(const f32x4*)(s2 + 2048 + u0);
    #pragma unroll
    for (int r = 0; r < 4; ++r) bg[r] = a[r] + c[r];
    a = *(const f32x4*)(s1 + 3072 + u0); c = *(const f32x4*)(s2 + 3072 + u0);
    #pragma unroll
    for (int r = 0; r < 4; ++r) bo[r] = a[r] + c[r];
  }
  float cr[4] = {0.f, 0.f, 0.f, 0.f};
  u32* tag_self = (layer ? f1 : f0) + ((u32)wv * 128u + (u32)lcu) * 8u;
  const u32* f0w = f0 + (u32)wv * 1024u;
  const u32* f1w = f1 + (u32)wv * 1024u;

  f32x16 acc;

  // poll all 128 class-w producer tags >= target (2 per lane, pipelined)
  auto poll = [&](const u32* fw, u32 target) {
    const u32* p1 = fw + (u32)lane * 8u;
    const u32* p2 = p1 + 512u;
    for (;;) {
      u32 v1, v2;
      asm volatile("global_load_dword %0, %2, off sc0 sc1\n\t"
                   "global_load_dword %1, %3, off sc0 sc1\n\t"
                   "s_waitcnt vmcnt(0)"
                   : "=v"(v1), "=v"(v2) : "v"(p1), "v"(p2) : "memory");
      if (__all((int)((v1 >= target) & (v2 >= target)))) break;
    }
  };

  // one MFMA: A = W col-frag from LDS (k-tile kt), B = h/x frag
  auto mfmaK = [&](short8 bf8, int kt) {
    short8 a = *(const short8*)(wcol + (((u32)(kt * 32 + hi * 16)) ^ swz));
    acc = __builtin_amdgcn_mfma_f32_32x32x16_bf16(a, bf8, acc, 0, 0, 0);
  };

  // nonlinearity fully in-lane; publish: store(sc01) -> vmcnt(0) -> tag
  auto nonlin_publish = [&](int t, u16* hist) {
    float hv[4];
    #pragma unroll
    for (int r = 0; r < 4; ++r) {
      float iv = acc[r] + bi[r];
      float fv = acc[4 + r] + bfr[r];
      float gv = acc[8 + r] + bg[r];
      float ov = acc[12 + r] + bo[r];
      float ii = 1.f / (1.f + __expf(-iv));
      float ff = 1.f / (1.f + __expf(-fv));
      float gt = 1.f - 2.f / (__expf(2.f * gv) + 1.f);
      float oo = 1.f / (1.f + __expf(-ov));
      cr[r] = ff * cr[r] + ii * gt;
      hv[r] = oo * (1.f - 2.f / (__expf(2.f * cr[r]) + 1.f));
    }
    u32x2 pk;
    pk.x = (u32)f2bf(hv[0]) | ((u32)f2bf(hv[1]) << 16);
    pk.y = (u32)f2bf(hv[2]) | ((u32)f2bf(hv[3]) << 16);
    u32* dst = (u32*)(hist + (size_t)(t + 1) * 65536 + (size_t)lcu * 512
                      + (size_t)b * 8 + 4 * hi);
    asm volatile("global_store_dwordx2 %0, %1, off sc0 sc1" :: "v"(dst), "v"(pk));
    asm volatile("s_waitcnt vmcnt(0)");                      // data ack'd at IC
    if (lane == 0)
      asm volatile("global_store_dword %0, %1, off sc0 sc1"
                   :: "v"(tag_self), "v"((u32)(t + 1)));
  };

  if (!layer) {
    // ---------------- layer 0: k-tiles 0-31 = x, 32-95 = h0prev ----------------
    for (int t = 0; t < 512; ++t) {
      #pragma unroll
      for (int r = 0; r < 16; ++r) acc[r] = 0.f;
      short8 X0[16], X1[16], H0g[16], H1g[16], H2g[16], H3g[16];
      const u16* xp = xb + (size_t)t * 32768 + (size_t)b * 512 + hi * 8;
      #pragma unroll
      for (int j = 0; j < 16; ++j) X0[j] = *(const short8*)(xp + j * 16);
      #pragma unroll
      for (int j = 0; j < 16; ++j) X1[j] = *(const short8*)(xp + 256 + j * 16);
      if (t > 0) {
        poll(f0w, (u32)t);
        const u16* hp = h0h + (size_t)t * 65536 + (size_t)b * 8;   // + chunk*512
        #pragma unroll
        for (int j = 0; j < 16; ++j) H0g[j] = *(const short8*)(hp + (size_t)(j * 2 + hi) * 512);
        #pragma unroll
        for (int j = 0; j < 16; ++j) H1g[j] = *(const short8*)(hp + (size_t)((16 + j) * 2 + hi) * 512);
        #pragma unroll
        for (int j = 0; j < 16; ++j) H2g[j] = *(const short8*)(hp + (size_t)((32 + j) * 2 + hi) * 512);
        #pragma unroll
        for (int j = 0; j < 16; ++j) H3g[j] = *(const short8*)(hp + (size_t)((48 + j) * 2 + hi) * 512);
      }
      #pragma unroll
      for (int j = 0; j < 16; ++j) mfmaK(X0[j], j);
      #pragma unroll
      for (int j = 0; j < 16; ++j) mfmaK(X1[j], 16 + j);
      if (t > 0) {
        #pragma unroll
        for (int j = 0; j < 16; ++j) mfmaK(H0g[j], 32 + j);
        #pragma unroll
        for (int j = 0; j < 16; ++j) mfmaK(H1g[j], 48 + j);
        #pragma unroll
        for (int j = 0; j < 16; ++j) mfmaK(H2g[j], 64 + j);
        #pragma unroll
        for (int j = 0; j < 16; ++j) mfmaK(H3g[j], 80 + j);
      }
      nonlin_publish(t, h0h);
    }
  } else {
    // ------------- layer 1: k-tiles 0-63 = h0cur, 64-127 = h1prev -------------
    for (int t = 0; t < 512; ++t) {
      #pragma unroll
      for (int r = 0; r < 16; ++r) acc[r] = 0.f;
      short8 A0[16], A1[16], A2[16], A3[16], B0[16], B1[16], B2[16], B3[16];
      if (t > 0) {
        poll(f1w, (u32)t);
        const u16* hp1 = h1h + (size_t)t * 65536 + (size_t)b * 8;
        #pragma unroll
        for (int j = 0; j < 16; ++j) A0[j] = *(const short8*)(hp1 + (size_t)(j * 2 + hi) * 512);
        #pragma unroll
        for (int j = 0; j < 16; ++j) A1[j] = *(const short8*)(hp1 + (size_t)((16 + j) * 2 + hi) * 512);
        #pragma unroll
        for (int j = 0; j < 16; ++j) A2[j] = *(const short8*)(hp1 + (size_t)((32 + j) * 2 + hi) * 512);
        #pragma unroll
        for (int j = 0; j < 16; ++j) A3[j] = *(const short8*)(hp1 + (size_t)((48 + j) * 2 + hi) * 512);
      }
      poll(f0w, (u32)(t + 1));
      const u16* hp0 = h0h + (size_t)(t + 1) * 65536 + (size_t)b * 8;
      #pragma unroll
      for (int j = 0; j < 16; ++j) B0[j] = *(const short8*)(hp0 + (size_t)(j * 2 + hi) * 512);
      #pragma unroll
      for (int j = 0; j < 16; ++j) B1[j] = *(const short8*)(hp0 + (size_t)((16 + j) * 2 + hi) * 512);
      if (t > 0) {
        #pragma unroll
        for (int j = 0; j < 16; ++j) mfmaK(A0[j], 64 + j);
        #pragma unroll
        for (int j = 0; j < 16; ++j) mfmaK(A1[j], 80 + j);
      }
      #pragma unroll
      for (int j = 0; j < 16; ++j) B2[j] = *(const short8*)(hp0 + (size_t)((32 + j) * 2 + hi) * 512);
      #pragma unroll
      for (int j = 0; j < 16; ++j) B3[j] = *(const short8*)(hp0 + (size_t)((48 + j) * 2 + hi) * 512);
      if (t > 0) {
        #pragma unroll
        for (int j = 0; j < 16; ++j) mfmaK(A2[j], 96 + j);
        #pragma unroll
        for (int j = 0; j < 16; ++j) mfmaK(A3[j], 112 + j);
      }
      #pragma unroll
      for (int j = 0; j < 16; ++j) mfmaK(B0[j], j);
      #pragma unroll
      for (int j = 0; j < 16; ++j) mfmaK(B1[j], 16 + j);
      #pragma unroll
      for (int j = 0; j < 16; ++j) mfmaK(B2[j], 32 + j);
      #pragma unroll
      for (int j = 0; j < 16; ++j) mfmaK(B3[j], 48 + j);
      nonlin_publish(t, h1h);
    }
  }

  // ---- FC + softmax epilogue: block 0, wave 0 (reads h1[511] = slot 512) ----
  if (cu == 0 && wv == 0) {
    #pragma unroll
    for (int j = 0; j < 4; ++j) {
      const u32* p = f1 + (u32)(lane + 64 * j) * 8u;
      for (;;) {
        u32 v;
        asm volatile("global_load_dword %0, %1, off sc0 sc1\n\ts_waitcnt vmcnt(0)"
                     : "=v"(v) : "v"(p) : "memory");
        if (v >= 512u) break;
      }
    }
    const u16* hb = h1h + (size_t)512 * 65536 + (size_t)lane * 8;
    float s0 = fc_b[0], s1 = fc_b[1];
    for (int c = 0; c < 128; ++c) {
      short8 hv8 = *(const short8*)(hb + (size_t)c * 512);
      #pragma unroll
      for (int e = 0; e < 8; ++e) {
        float hvv = bf2f((u16)hv8[e]);
        s0 += hvv * fc_w[c * 8 + e];
        s1 += hvv * fc_w[1024 + c * 8 + e];
      }
    }
    float mx = fmaxf(s0, s1);
    float e0 = __expf(s0 - mx), e1 = __expf(s1 - mx);
    float inv = 1.f / (e0 + e1);
    out[lane * 2] = e0 * inv;
    out[lane * 2 + 1] = e1 * inv;
  }
}

extern "C" void kernel_launch(void* const* d_in, const int* in_sizes, int n_in,
                              void* d_out, int out_size, void* d_ws, size_t ws_size,
                              hipStream_t stream) {
  const float* x    = (const float*)d_in[0];
  const float* wih0 = (const float*)d_in[1];
  const float* whh0 = (const float*)d_in[2];
  const float* bih0 = (const float*)d_in[3];
  const float* bhh0 = (const float*)d_in[4];
  const float* wih1 = (const float*)d_in[5];
  const float* whh1 = (const float*)d_in[6];
  const float* bih1 = (const float*)d_in[7];
  const float* bhh1 = (const float*)d_in[8];
  const float* fcw  = (const float*)d_in[9];
  const float* fcb  = (const float*)d_in[10];
  float* out = (float*)d_out;
  char* ws = (char*)d_ws;

  u16* xb  = (u16*)(ws + XB_OFF);
  u16* h0h = (u16*)(ws + H0_OFF);
  u16* h1h = (u16*)(ws + H1_OFF);
  u32* f0  = (u32*)(ws + F0_OFF);
  u32* f1  = (u32*)(ws + F1_OFF);

  (void)hipFuncSetAttribute((const void*)lstm_persist,
      hipFuncAttributeMaxDynamicSharedMemorySize, LDS_TOTAL);

  hipMemsetAsync(ws + F0_OFF, 0, FLAGS_LEN, stream);   // zero step tags
  prep_x<<<8192, 256, 0, stream>>>(x, xb);
  lstm_persist<<<256, 192, LDS_TOTAL, stream>>>(
      (const u16*)xb, wih0, whh0, bih0, bhh0, wih1, whh1, bih1, bhh1,
      h0h, h1h, f0, f1, fcw, fcb, out);
}